// Round 9
// baseline (29.435 us; speedup 1.0000x reference)
//
#include <hip/hip_runtime.h>

#define Bn 4
#define Ln 512
#define Hn 768
#define Sn 100
#define Rn 100
#define En 128
#define TEn 8
#define TRn 6
#define NEGF (-1e20f)
#define H4 (Hn / 4)        // 192
#define E4 (En / 4)        // 32
#define NTHR 640           // 10 waves

__device__ __forceinline__ float4 fmax4(float4 a, float4 b) {
    return make_float4(fmaxf(a.x, b.x), fmaxf(a.y, b.y),
                       fmaxf(a.z, b.z), fmaxf(a.w, b.w));
}

// wave-level contiguous-span scan -> {start, end} (valid in all lanes)
__device__ __forceinline__ void scan_span(const int* __restrict__ mask,
                                          int lane, int* start, int* end) {
    const int4* m4 = (const int4*)(mask + lane * 8);
    int4 a = m4[0], c = m4[1];
    int mm[8] = {a.x, a.y, a.z, a.w, c.x, c.y, c.z, c.w};
    int first = 0x7fffffff, last = -1;
    #pragma unroll
    for (int r = 0; r < 8; ++r) {
        if (mm[r] != 0) {
            int row = lane * 8 + r;
            first = min(first, row);
            last = max(last, row);
        }
    }
    #pragma unroll
    for (int off = 1; off < 64; off <<= 1) {
        first = min(first, __shfl_xor(first, off, 64));
        last = max(last, __shfl_xor(last, off, 64));
    }
    *start = first;
    *end = last + 1;
}

// max over rows [s,e) of this thread's float4 column; 4 independent accs
__device__ __forceinline__ float4 stream_max(const float4* __restrict__ hb4,
                                             int s, int e) {
    float4 m0 = make_float4(NEGF, NEGF, NEGF, NEGF);
    float4 m1 = m0, m2 = m0, m3 = m0;
    int r = s;
    for (; r + 4 <= e; r += 4) {
        m0 = fmax4(m0, hb4[(size_t)(r + 0) * H4]);
        m1 = fmax4(m1, hb4[(size_t)(r + 1) * H4]);
        m2 = fmax4(m2, hb4[(size_t)(r + 2) * H4]);
        m3 = fmax4(m3, hb4[(size_t)(r + 3) * H4]);
    }
    for (; r < e; ++r)
        m0 = fmax4(m0, hb4[(size_t)r * H4]);
    return fmax4(fmax4(m0, m1), fmax4(m2, m3));
}

// ---------------------------------------------------------------------------
// Single kernel: 800 blocks x 640 threads, fully segment-parallel, all span
// maxes recomputed directly from hid (L2-resident).
//  entity blk: [0,192) entity | [192,384) ctx | [384,416) size
//  rel blk:    [0,192) relctx | [192,384) e0 | [384,576) e1 | [576,640) s0,s1
// ---------------------------------------------------------------------------
__global__ void __launch_bounds__(NTHR)
fused_kernel(const float* __restrict__ hid,
             const int* __restrict__ ent_mask,
             const int* __restrict__ rel_mask,
             const int* __restrict__ samp_mask,
             const int* __restrict__ relations,
             const float* __restrict__ size_emb,
             const float* __restrict__ span_w,
             const float* __restrict__ span_b,
             const float* __restrict__ rel_w,
             const float* __restrict__ rel_b,
             float* __restrict__ out_ent,
             float* __restrict__ out_rel) {
    int blk = blockIdx.x;
    int tid = threadIdx.x;
    int lane = tid & 63, wv = tid >> 6;

    __shared__ int se[3][2];
    __shared__ float red[10][TEn];

    float acc[TEn];
    #pragma unroll
    for (int t = 0; t < TEn; ++t) acc[t] = 0.0f;

    if (blk < Bn * Sn) {
        // ================= entity logit block =================
        int b = blk / Sn;
        float w32[4 * TEn];
        if (tid < 384 + E4) {
            const float4* wp = (const float4*)(span_w + (size_t)tid * 4 * TEn);
            float4* wreg = (float4*)w32;
            #pragma unroll
            for (int i = 0; i < TEn; ++i) wreg[i] = wp[i];
        }
        if (wv == 0) {
            int s0, e0;
            scan_span(ent_mask + (size_t)blk * Ln, lane, &s0, &e0);
            if (lane == 0) { se[0][0] = s0; se[0][1] = e0; }
        }
        __syncthreads();
        int start = se[0][0], end = se[0][1];
        int cnt = end - start;

        const float4* hb4 = (const float4*)(hid + (size_t)b * Ln * Hn);
        float4 v = make_float4(0.f, 0.f, 0.f, 0.f);
        bool active = true;
        if (tid < 192) {
            v = stream_max(hb4 + tid, start, end);
        } else if (tid < 384) {
            v = hb4[tid - 192];                               // ctx = row 0
        } else if (tid < 384 + E4) {
            v = ((const float4*)(size_emb + (size_t)cnt * En))[tid - 384];
        } else {
            active = false;
        }
        if (active) {
            const float* vp = &v.x;
            #pragma unroll
            for (int j = 0; j < 4; ++j)
                #pragma unroll
                for (int t = 0; t < TEn; ++t)
                    acc[t] += vp[j] * w32[j * TEn + t];
        }

        #pragma unroll
        for (int t = 0; t < TEn; ++t)
            #pragma unroll
            for (int off = 32; off > 0; off >>= 1)
                acc[t] += __shfl_down(acc[t], off, 64);
        if (lane == 0) {
            #pragma unroll
            for (int t = 0; t < TEn; ++t) red[wv][t] = acc[t];
        }
        __syncthreads();
        if (tid < TEn) {
            float s = span_b[tid];
            #pragma unroll
            for (int w = 0; w < 10; ++w) s += red[w][tid];
            out_ent[(size_t)blk * TEn + tid] = s;
        }
    } else {
        // ================= relation logit block =================
        int rblk = blk - Bn * Sn;              // b*R + r
        int b = rblk / Rn;
        int a0 = relations[rblk * 2 + 0];
        int a1 = relations[rblk * 2 + 1];
        bool samp = (samp_mask[rblk] == 1);

        float w24[4 * TRn];
        {
            const float4* wp = (const float4*)(rel_w + (size_t)tid * 4 * TRn);
            float4* wreg = (float4*)w24;
            #pragma unroll
            for (int i = 0; i < TRn; ++i) wreg[i] = wp[i];
        }

        if (wv == 0) {
            if (!samp) {
                int s0, e0;
                scan_span(rel_mask + (size_t)rblk * Ln, lane, &s0, &e0);
                if (lane == 0) { se[0][0] = s0; se[0][1] = e0; }
            }
        } else if (wv == 1) {
            int s1, e1;
            scan_span(ent_mask + ((size_t)b * Sn + a0) * Ln, lane, &s1, &e1);
            if (lane == 0) { se[1][0] = s1; se[1][1] = e1; }
        } else if (wv == 2) {
            int s2, e2;
            scan_span(ent_mask + ((size_t)b * Sn + a1) * Ln, lane, &s2, &e2);
            if (lane == 0) { se[2][0] = s2; se[2][1] = e2; }
        }
        __syncthreads();
        int cnt0 = se[1][1] - se[1][0];
        int cnt1 = se[2][1] - se[2][0];

        const float4* hb4 = (const float4*)(hid + (size_t)b * Ln * Hn);
        float4 v = make_float4(0.f, 0.f, 0.f, 0.f);
        bool active = true;
        if (tid < 192) {
            if (samp) active = false;
            else v = stream_max(hb4 + tid, se[0][0], se[0][1]);
        } else if (tid < 384) {
            int u = tid - 192;
            v = stream_max(hb4 + u, se[1][0], se[1][1]);
        } else if (tid < 576) {
            int u = tid - 384;
            v = stream_max(hb4 + u, se[2][0], se[2][1]);
        } else if (tid < 576 + E4) {
            v = ((const float4*)(size_emb + (size_t)cnt0 * En))[tid - 576];
        } else {
            v = ((const float4*)(size_emb + (size_t)cnt1 * En))[tid - 576 - E4];
        }
        if (active) {
            const float* vp = &v.x;
            #pragma unroll
            for (int j = 0; j < 4; ++j)
                #pragma unroll
                for (int t = 0; t < TRn; ++t)
                    acc[t] += vp[j] * w24[j * TRn + t];
        }

        #pragma unroll
        for (int t = 0; t < TRn; ++t)
            #pragma unroll
            for (int off = 32; off > 0; off >>= 1)
                acc[t] += __shfl_down(acc[t], off, 64);
        if (lane == 0) {
            #pragma unroll
            for (int t = 0; t < TRn; ++t) red[wv][t] = acc[t];
        }
        __syncthreads();
        if (tid < TRn) {
            float s = rel_b[tid];
            #pragma unroll
            for (int w = 0; w < 10; ++w) s += red[w][tid];
            out_rel[(size_t)rblk * TRn + tid] = s;
        }
    }
}

extern "C" void kernel_launch(void* const* d_in, const int* in_sizes, int n_in,
                              void* d_out, int out_size, void* d_ws, size_t ws_size,
                              hipStream_t stream) {
    const float* hid       = (const float*)d_in[0];   // (B,L,H)
    const int*   ent_mask  = (const int*)d_in[1];     // (B,S,L)
    const int*   relations = (const int*)d_in[2];     // (B,R,2)
    const int*   rel_mask  = (const int*)d_in[3];     // (B,R,L)
    const int*   samp_mask = (const int*)d_in[4];     // (B,R)
    const float* size_emb  = (const float*)d_in[5];   // (100,E)
    const float* span_w    = (const float*)d_in[6];   // (2H+E, TE)
    const float* span_b    = (const float*)d_in[7];   // (TE,)
    const float* rel_w     = (const float*)d_in[8];   // (3H+2E, TR)
    const float* rel_b     = (const float*)d_in[9];   // (TR,)

    float* out = (float*)d_out;
    float* out_ent = out;                       // (B,S,TE)
    float* out_rel = out + Bn * Sn * TEn;       // (B,R,TR)

    fused_kernel<<<Bn * (Sn + Rn), NTHR, 0, stream>>>(
        hid, ent_mask, rel_mask, samp_mask, relations, size_emb,
        span_w, span_b, rel_w, rel_b, out_ent, out_rel);
}

// Round 10
// 25.064 us; speedup vs baseline: 1.1744x; 1.1744x over previous
//
#include <hip/hip_runtime.h>

#define Bn 4
#define Ln 512
#define Hn 768
#define Sn 100
#define Rn 100
#define En 128
#define TEn 8
#define TRn 6
#define NEGF (-1e20f)
#define H4 (Hn / 4)        // 192
#define E4 (En / 4)        // 32
#define NTHR 640           // 10 waves

__device__ __forceinline__ float4 fmax4(float4 a, float4 b) {
    return make_float4(fmaxf(a.x, b.x), fmaxf(a.y, b.y),
                       fmaxf(a.z, b.z), fmaxf(a.w, b.w));
}

// wave-level contiguous-span scan -> {start, end} (valid in all lanes)
__device__ __forceinline__ void scan_span(const int* __restrict__ mask,
                                          int lane, int* start, int* end) {
    const int4* m4 = (const int4*)(mask + lane * 8);
    int4 a = m4[0], c = m4[1];
    int mm[8] = {a.x, a.y, a.z, a.w, c.x, c.y, c.z, c.w};
    int first = 0x7fffffff, last = -1;
    #pragma unroll
    for (int r = 0; r < 8; ++r) {
        if (mm[r] != 0) {
            int row = lane * 8 + r;
            first = min(first, row);
            last = max(last, row);
        }
    }
    #pragma unroll
    for (int off = 1; off < 64; off <<= 1) {
        first = min(first, __shfl_xor(first, off, 64));
        last = max(last, __shfl_xor(last, off, 64));
    }
    *start = first;
    *end = last + 1;
}

// ---------------------------------------------------------------------------
// A: one block per span. 640 threads:
//   grp 0/1/2 (192 thr each): row-phase g streams rows start+g, start+g+3,...
//     of this span; LDS-combine -> full span max per column.
//   entity block dots: grp0 -> span_w[0:H] (8-wide, entity logit part),
//     grp1 -> rel_w[H:2H] (p0, 6-wide), grp2 -> rel_w[2H:3H] (p1),
//     wave 9 -> ctx @ span_w[H:2H] + size_emb[cnt] @ span_w[2H:] (8-wide).
//   relation block dots: grp0 -> rel_w[0:H] (relctx partial, 6-wide).
// Entity logits finished here; p0/p1/relpart/entcnt go to workspace.
// ---------------------------------------------------------------------------
__global__ void __launch_bounds__(NTHR)
span_kernel(const float* __restrict__ hid,
            const int* __restrict__ ent_mask,
            const int* __restrict__ rel_mask,
            const int* __restrict__ samp_mask,
            const float* __restrict__ size_emb,
            const float* __restrict__ span_w,
            const float* __restrict__ span_b,
            const float* __restrict__ rel_w,
            float* __restrict__ relpart,
            float* __restrict__ p0ws,
            float* __restrict__ p1ws,
            int* __restrict__ entcnt,
            float* __restrict__ out_ent) {
    int blk = blockIdx.x;
    int tid = threadIdx.x;
    int lane = tid & 63, wv = tid >> 6;
    int grp = tid / 192;               // 0,1,2 row-phases; 3 == wave 9
    int u = tid - grp * 192;

    __shared__ float4 sh[3][192];
    __shared__ float red[10][TEn];

    bool is_ent = blk < Bn * Sn;
    int b, rblk = 0;
    const int* mask;
    if (is_ent) {
        b = blk / Sn;
        mask = ent_mask + (size_t)blk * Ln;
    } else {
        rblk = blk - Bn * Sn;          // b*R + r
        b = rblk / Rn;
        if (samp_mask[rblk] == 1) {    // zeroed relctx -> partial is 0
            if (tid < TRn) relpart[(size_t)rblk * TRn + tid] = 0.f;
            return;
        }
        mask = rel_mask + (size_t)rblk * Ln;
    }

    // every wave scans redundantly (no barrier needed before streaming)
    int start, end;
    scan_span(mask, lane, &start, &end);
    int cnt = end - start;
    if (is_ent && tid == 0) entcnt[blk] = cnt;

    const float4* hb4 = (const float4*)(hid + (size_t)b * Ln * Hn);

    if (grp < 3) {                     // stream this phase's rows
        const float4* col = hb4 + u;
        float4 m0 = make_float4(NEGF, NEGF, NEGF, NEGF), m1 = m0;
        int r = start + grp;
        for (; r + 3 < end; r += 6) {
            m0 = fmax4(m0, col[(size_t)r * H4]);
            m1 = fmax4(m1, col[(size_t)(r + 3) * H4]);
        }
        if (r < end) m0 = fmax4(m0, col[(size_t)r * H4]);
        sh[grp][u] = fmax4(m0, m1);
    }
    __syncthreads();

    float acc[TEn];
    #pragma unroll
    for (int t = 0; t < TEn; ++t) acc[t] = 0.f;

    bool do_red;
    if (grp < 3) {
        do_red = is_ent || (grp == 0);
        if (do_red) {
            float4 v = fmax4(fmax4(sh[0][u], sh[1][u]), sh[2][u]);
            const float* vp = &v.x;
            if (is_ent) {
                if (grp == 0) {
                    #pragma unroll
                    for (int j = 0; j < 4; ++j) {
                        const float* wr = span_w + (size_t)(4 * u + j) * TEn;
                        #pragma unroll
                        for (int t = 0; t < TEn; ++t) acc[t] += vp[j] * wr[t];
                    }
                } else {
                    int base = (grp == 1 ? Hn : 2 * Hn) + 4 * u;
                    #pragma unroll
                    for (int j = 0; j < 4; ++j) {
                        const float* wr = rel_w + (size_t)(base + j) * TRn;
                        #pragma unroll
                        for (int t = 0; t < TRn; ++t) acc[t] += vp[j] * wr[t];
                    }
                }
            } else {                   // relation: relctx @ rel_w[0:H]
                #pragma unroll
                for (int j = 0; j < 4; ++j) {
                    const float* wr = rel_w + (size_t)(4 * u + j) * TRn;
                    #pragma unroll
                    for (int t = 0; t < TRn; ++t) acc[t] += vp[j] * wr[t];
                }
            }
        }
    } else {
        // wave 9: entity blocks only — ctx and size segments
        do_red = is_ent;
        if (is_ent) {
            #pragma unroll
            for (int cc = 0; cc < 3; ++cc) {
                int c = lane + cc * 64;
                float4 v = hb4[c];                     // ctx = row 0
                const float* vp = &v.x;
                #pragma unroll
                for (int j = 0; j < 4; ++j) {
                    const float* wr = span_w + (size_t)(Hn + 4 * c + j) * TEn;
                    #pragma unroll
                    for (int t = 0; t < TEn; ++t) acc[t] += vp[j] * wr[t];
                }
            }
            if (lane < E4) {
                float4 sv = ((const float4*)(size_emb + (size_t)cnt * En))[lane];
                const float* sp = &sv.x;
                #pragma unroll
                for (int j = 0; j < 4; ++j) {
                    const float* wr = span_w + (size_t)(2 * Hn + 4 * lane + j) * TEn;
                    #pragma unroll
                    for (int t = 0; t < TEn; ++t) acc[t] += sp[j] * wr[t];
                }
            }
        }
    }

    if (do_red) {
        #pragma unroll
        for (int t = 0; t < TEn; ++t)
            #pragma unroll
            for (int off = 32; off > 0; off >>= 1)
                acc[t] += __shfl_down(acc[t], off, 64);
        if (lane == 0) {
            #pragma unroll
            for (int t = 0; t < TEn; ++t) red[wv][t] = acc[t];
        }
    }
    __syncthreads();

    if (is_ent) {
        if (tid < TEn) {
            out_ent[(size_t)blk * TEn + tid] = span_b[tid]
                + red[0][tid] + red[1][tid] + red[2][tid] + red[9][tid];
        } else if (tid >= 64 && tid < 64 + TRn) {
            int t = tid - 64;
            p0ws[(size_t)blk * TRn + t] = red[3][t] + red[4][t] + red[5][t];
        } else if (tid >= 128 && tid < 128 + TRn) {
            int t = tid - 128;
            p1ws[(size_t)blk * TRn + t] = red[6][t] + red[7][t] + red[8][t];
        }
    } else {
        if (tid < TRn)
            relpart[(size_t)rblk * TRn + tid] =
                red[0][tid] + red[1][tid] + red[2][tid];
    }
}

// ---------------------------------------------------------------------------
// B: relation combine. One 64-thread block per (b,r):
//   out_rel = relpart + p0[a0] + p1[a1]
//             + size_emb[cnt0]@rel_w[3H:3H+E] + size_emb[cnt1]@rel_w[3H+E:] + b
// ---------------------------------------------------------------------------
__global__ void __launch_bounds__(64)
combine_kernel(const int* __restrict__ relations,
               const int* __restrict__ entcnt,
               const float* __restrict__ size_emb,
               const float* __restrict__ rel_w,
               const float* __restrict__ rel_b,
               const float* __restrict__ relpart,
               const float* __restrict__ p0ws,
               const float* __restrict__ p1ws,
               float* __restrict__ out_rel) {
    int rblk = blockIdx.x;             // b*R + r
    int b = rblk / Rn;
    int lane = threadIdx.x;
    int a0 = relations[rblk * 2 + 0];
    int a1 = relations[rblk * 2 + 1];
    int e0 = b * Sn + a0, e1 = b * Sn + a1;

    // lanes 0-31: size_a0 segment; lanes 32-63: size_a1 segment
    int c = lane & 31;
    int srow = entcnt[(lane < 32) ? e0 : e1];
    int wbase = (lane < 32) ? 3 * Hn : 3 * Hn + En;

    float acc[TRn];
    #pragma unroll
    for (int t = 0; t < TRn; ++t) acc[t] = 0.f;

    float4 sv = ((const float4*)(size_emb + (size_t)srow * En))[c];
    const float* sp = &sv.x;
    #pragma unroll
    for (int j = 0; j < 4; ++j) {
        const float* wr = rel_w + (size_t)(wbase + 4 * c + j) * TRn;
        #pragma unroll
        for (int t = 0; t < TRn; ++t) acc[t] += sp[j] * wr[t];
    }

    #pragma unroll
    for (int t = 0; t < TRn; ++t)
        #pragma unroll
        for (int off = 32; off > 0; off >>= 1)
            acc[t] += __shfl_down(acc[t], off, 64);

    if (lane == 0) {
        #pragma unroll
        for (int t = 0; t < TRn; ++t) {
            out_rel[(size_t)rblk * TRn + t] = acc[t]
                + relpart[(size_t)rblk * TRn + t]
                + p0ws[(size_t)e0 * TRn + t]
                + p1ws[(size_t)e1 * TRn + t]
                + rel_b[t];
        }
    }
}

extern "C" void kernel_launch(void* const* d_in, const int* in_sizes, int n_in,
                              void* d_out, int out_size, void* d_ws, size_t ws_size,
                              hipStream_t stream) {
    const float* hid       = (const float*)d_in[0];   // (B,L,H)
    const int*   ent_mask  = (const int*)d_in[1];     // (B,S,L)
    const int*   relations = (const int*)d_in[2];     // (B,R,2)
    const int*   rel_mask  = (const int*)d_in[3];     // (B,R,L)
    const int*   samp_mask = (const int*)d_in[4];     // (B,R)
    const float* size_emb  = (const float*)d_in[5];   // (100,E)
    const float* span_w    = (const float*)d_in[6];   // (2H+E, TE)
    const float* span_b    = (const float*)d_in[7];   // (TE,)
    const float* rel_w     = (const float*)d_in[8];   // (3H+2E, TR)
    const float* rel_b     = (const float*)d_in[9];   // (TR,)

    float* out = (float*)d_out;
    float* out_ent = out;                       // (B,S,TE)
    float* out_rel = out + Bn * Sn * TEn;       // (B,R,TR)

    char* ws = (char*)d_ws;
    float* relpart = (float*)ws;                              // B*R*TR
    float* p0ws    = relpart + (size_t)Bn * Rn * TRn;         // B*S*TR
    float* p1ws    = p0ws + (size_t)Bn * Sn * TRn;            // B*S*TR
    int*   entcnt  = (int*)(p1ws + (size_t)Bn * Sn * TRn);    // B*S

    span_kernel<<<Bn * (Sn + Rn), NTHR, 0, stream>>>(
        hid, ent_mask, rel_mask, samp_mask, size_emb, span_w, span_b,
        rel_w, relpart, p0ws, p1ws, entcnt, out_ent);

    combine_kernel<<<Bn * Rn, 64, 0, stream>>>(
        relations, entcnt, size_emb, rel_w, rel_b,
        relpart, p0ws, p1ws, out_rel);
}

// Round 11
// 23.815 us; speedup vs baseline: 1.2360x; 1.0525x over previous
//
#include <hip/hip_runtime.h>

#define Bn 4
#define Ln 512
#define Hn 768
#define Sn 100
#define Rn 100
#define En 128
#define TEn 8
#define TRn 6
#define NEGF (-1e20f)
#define W 8
#define NBLK (Ln / W)      // 64
#define H4 (Hn / 4)        // 192
#define E4 (En / 4)        // 32
#define NTHR 640           // 10 waves

__device__ __forceinline__ float4 fmax4(float4 a, float4 b) {
    return make_float4(fmaxf(a.x, b.x), fmaxf(a.y, b.y),
                       fmaxf(a.z, b.z), fmaxf(a.w, b.w));
}

// ---------------------------------------------------------------------------
// N1: bmax[b][j][:] = max over rows 8j..8j+7 of hid[b]. 256 blocks x 192 thr.
// ---------------------------------------------------------------------------
__global__ void __launch_bounds__(192)
blockmax_kernel(const float* __restrict__ hid, float* __restrict__ bmax) {
    int bj = blockIdx.x;                   // b*NBLK + j
    int b = bj / NBLK, j = bj % NBLK;
    int tid = threadIdx.x;
    const float4* src = (const float4*)(hid + ((size_t)b * Ln + j * W) * Hn);
    float4 m0 = src[tid];
    float4 m1 = src[(size_t)H4 + tid];
    #pragma unroll
    for (int r = 2; r < W; r += 2) {
        m0 = fmax4(m0, src[(size_t)r * H4 + tid]);
        m1 = fmax4(m1, src[(size_t)(r + 1) * H4 + tid]);
    }
    ((float4*)(bmax + (size_t)bj * Hn))[tid] = fmax4(m0, m1);
}

// wave-level contiguous-span scan -> {start, end} (valid in all lanes)
__device__ __forceinline__ void scan_span(const int* __restrict__ mask,
                                          int lane, int* start, int* end) {
    const int4* m4 = (const int4*)(mask + lane * 8);
    int4 a = m4[0], c = m4[1];
    int mm[8] = {a.x, a.y, a.z, a.w, c.x, c.y, c.z, c.w};
    int first = 0x7fffffff, last = -1;
    #pragma unroll
    for (int r = 0; r < 8; ++r) {
        if (mm[r] != 0) {
            int row = lane * 8 + r;
            first = min(first, row);
            last = max(last, row);
        }
    }
    #pragma unroll
    for (int off = 1; off < 64; off <<= 1) {
        first = min(first, __shfl_xor(first, off, 64));
        last = max(last, __shfl_xor(last, off, 64));
    }
    *start = first;
    *end = last + 1;
}

// group-split hierarchical span max: group grp (0..2) takes every 3rd item
// of {mid bmax blocks, head rows, tail rows}. col ptrs pre-offset by +u.
__device__ __forceinline__ float4 gmax(const float4* __restrict__ hb4,
                                       const float4* __restrict__ bm4,
                                       int start, int end, int grp) {
    float4 m0 = make_float4(NEGF, NEGF, NEGF, NEGF), m1 = m0;
    int jstart = (start + 7) >> 3, jend = end >> 3;
    if (jstart >= jend) {                  // short span: raw rows only
        for (int r = start + grp; r < end; r += 6) {
            m0 = fmax4(m0, hb4[(size_t)r * H4]);
            int r2 = r + 3;
            if (r2 < end) m1 = fmax4(m1, hb4[(size_t)r2 * H4]);
        }
        return fmax4(m0, m1);
    }
    for (int j = jstart + grp; j < jend; j += 3)
        m0 = fmax4(m0, bm4[(size_t)j * H4]);
    for (int r = start + grp; r < jstart * W; r += 3)
        m1 = fmax4(m1, hb4[(size_t)r * H4]);
    for (int r = jend * W + grp; r < end; r += 3)
        m0 = fmax4(m0, hb4[(size_t)r * H4]);
    return fmax4(m0, m1);
}

// ---------------------------------------------------------------------------
// N2: one block per span, 640 threads. One hierarchical span-max, 3-way
// group-split, then parallel dots:
//  entity blk: grp0 -> ent-logit span part (8w), grp1 -> p0 = e@rel_w[H:2H],
//   grp2 -> p1 = e@rel_w[2H:3H], wave9 -> ctx+size spans (8w) and
//   size@rel_w[3H:3H+E] (p0 part), size@rel_w[3H+E:] (p1 part).
//  rel blk: grp0 -> relctx partial (6w); zeros if sample-masked.
// ---------------------------------------------------------------------------
__global__ void __launch_bounds__(NTHR)
span_kernel(const float* __restrict__ hid,
            const int* __restrict__ ent_mask,
            const int* __restrict__ rel_mask,
            const int* __restrict__ samp_mask,
            const float* __restrict__ size_emb,
            const float* __restrict__ span_w,
            const float* __restrict__ span_b,
            const float* __restrict__ rel_w,
            const float* __restrict__ bmax,
            float* __restrict__ relpart,
            float* __restrict__ p0ws,
            float* __restrict__ p1ws,
            float* __restrict__ out_ent) {
    int blk = blockIdx.x;
    int tid = threadIdx.x;
    int lane = tid & 63, wv = tid >> 6;
    int grp = tid / 192;               // 0,1,2 row groups; 3 == wave 9
    int u = tid - grp * 192;

    __shared__ float4 sh[3][192];
    __shared__ float redA[9][TEn];     // waves 0-8 (grp dots)
    __shared__ float redW[3][TEn];     // wave 9: ctx+size-span / size-p0 / size-p1

    bool is_ent = blk < Bn * Sn;
    int b, rblk = 0;
    const int* mask;
    if (is_ent) {
        b = blk / Sn;
        mask = ent_mask + (size_t)blk * Ln;
    } else {
        rblk = blk - Bn * Sn;          // b*R + r
        b = rblk / Rn;
        if (samp_mask[rblk] == 1) {    // zeroed relctx -> partial = 0
            if (tid < TRn) relpart[(size_t)rblk * TRn + tid] = 0.f;
            return;
        }
        mask = rel_mask + (size_t)rblk * Ln;
    }

    int start, end;
    scan_span(mask, lane, &start, &end);
    int cnt = end - start;

    const float4* hb4 = (const float4*)(hid + (size_t)b * Ln * Hn);
    const float4* bm4 = (const float4*)(bmax + (size_t)b * NBLK * Hn);

    if (grp < 3)
        sh[grp][u] = gmax(hb4 + u, bm4 + u, start, end, grp);
    __syncthreads();

    float acc[TEn];
    #pragma unroll
    for (int t = 0; t < TEn; ++t) acc[t] = 0.f;
    float acc2[TRn], acc3[TRn];
    #pragma unroll
    for (int t = 0; t < TRn; ++t) { acc2[t] = 0.f; acc3[t] = 0.f; }

    if (grp < 3) {
        bool active = is_ent || (grp == 0);
        if (active) {
            float4 v = fmax4(fmax4(sh[0][u], sh[1][u]), sh[2][u]);
            const float* vp = &v.x;
            if (is_ent) {
                if (grp == 0) {                    // entity @ span_w[0:H]
                    #pragma unroll
                    for (int j = 0; j < 4; ++j) {
                        const float* wr = span_w + (size_t)(4 * u + j) * TEn;
                        #pragma unroll
                        for (int t = 0; t < TEn; ++t) acc[t] += vp[j] * wr[t];
                    }
                } else {                           // e @ rel_w[H:2H] or [2H:3H]
                    int base = (grp == 1 ? Hn : 2 * Hn) + 4 * u;
                    #pragma unroll
                    for (int j = 0; j < 4; ++j) {
                        const float* wr = rel_w + (size_t)(base + j) * TRn;
                        #pragma unroll
                        for (int t = 0; t < TRn; ++t) acc[t] += vp[j] * wr[t];
                    }
                }
            } else {                               // relctx @ rel_w[0:H]
                #pragma unroll
                for (int j = 0; j < 4; ++j) {
                    const float* wr = rel_w + (size_t)(4 * u + j) * TRn;
                    #pragma unroll
                    for (int t = 0; t < TRn; ++t) acc[t] += vp[j] * wr[t];
                }
            }
        }
        #pragma unroll
        for (int t = 0; t < TEn; ++t)
            #pragma unroll
            for (int off = 32; off > 0; off >>= 1)
                acc[t] += __shfl_down(acc[t], off, 64);
        if (lane == 0) {
            #pragma unroll
            for (int t = 0; t < TEn; ++t) redA[wv][t] = acc[t];
        }
    } else if (is_ent) {
        // wave 9: ctx @ span_w[H:2H] (3 cols/lane) + size segments
        #pragma unroll
        for (int cc = 0; cc < 3; ++cc) {
            int c = lane + cc * 64;
            float4 v = hb4[c];                     // ctx = row 0
            const float* vp = &v.x;
            #pragma unroll
            for (int j = 0; j < 4; ++j) {
                const float* wr = span_w + (size_t)(Hn + 4 * c + j) * TEn;
                #pragma unroll
                for (int t = 0; t < TEn; ++t) acc[t] += vp[j] * wr[t];
            }
        }
        if (lane < E4) {
            float4 sv = ((const float4*)(size_emb + (size_t)cnt * En))[lane];
            const float* sp = &sv.x;
            #pragma unroll
            for (int j = 0; j < 4; ++j) {
                const float* w1 = span_w + (size_t)(2 * Hn + 4 * lane + j) * TEn;
                const float* w2 = rel_w + (size_t)(3 * Hn + 4 * lane + j) * TRn;
                const float* w3 = rel_w + (size_t)(3 * Hn + En + 4 * lane + j) * TRn;
                #pragma unroll
                for (int t = 0; t < TEn; ++t) acc[t] += sp[j] * w1[t];
                #pragma unroll
                for (int t = 0; t < TRn; ++t) { acc2[t] += sp[j] * w2[t];
                                                acc3[t] += sp[j] * w3[t]; }
            }
        }
        #pragma unroll
        for (int t = 0; t < TEn; ++t)
            #pragma unroll
            for (int off = 32; off > 0; off >>= 1)
                acc[t] += __shfl_down(acc[t], off, 64);
        #pragma unroll
        for (int t = 0; t < TRn; ++t)
            #pragma unroll
            for (int off = 32; off > 0; off >>= 1) {
                acc2[t] += __shfl_down(acc2[t], off, 64);
                acc3[t] += __shfl_down(acc3[t], off, 64);
            }
        if (lane == 0) {
            #pragma unroll
            for (int t = 0; t < TEn; ++t) redW[0][t] = acc[t];
            #pragma unroll
            for (int t = 0; t < TRn; ++t) { redW[1][t] = acc2[t];
                                            redW[2][t] = acc3[t]; }
        }
    }
    __syncthreads();

    if (is_ent) {
        if (tid < TEn) {
            out_ent[(size_t)blk * TEn + tid] = span_b[tid]
                + redA[0][tid] + redA[1][tid] + redA[2][tid] + redW[0][tid];
        } else if (tid >= 64 && tid < 64 + TRn) {
            int t = tid - 64;
            p0ws[(size_t)blk * TRn + t] =
                redA[3][t] + redA[4][t] + redA[5][t] + redW[1][t];
        } else if (tid >= 128 && tid < 128 + TRn) {
            int t = tid - 128;
            p1ws[(size_t)blk * TRn + t] =
                redA[6][t] + redA[7][t] + redA[8][t] + redW[2][t];
        }
    } else {
        if (tid < TRn)
            relpart[(size_t)rblk * TRn + tid] =
                redA[0][tid] + redA[1][tid] + redA[2][tid];
    }
}

// ---------------------------------------------------------------------------
// N3: out_rel[b,r,t] = relpart[b,r,t] + p0[b,a0,t] + p1[b,a1,t] + rel_b[t]
// 2400 outputs, flat. 10 blocks x 256 threads.
// ---------------------------------------------------------------------------
__global__ void __launch_bounds__(256)
combine_kernel(const int* __restrict__ relations,
               const float* __restrict__ rel_b,
               const float* __restrict__ relpart,
               const float* __restrict__ p0ws,
               const float* __restrict__ p1ws,
               float* __restrict__ out_rel) {
    int idx = blockIdx.x * 256 + threadIdx.x;
    if (idx >= Bn * Rn * TRn) return;
    int r = idx / TRn, t = idx - r * TRn;  // r = b*R + rr
    int b = r / Rn;
    int a0 = relations[r * 2 + 0];
    int a1 = relations[r * 2 + 1];
    out_rel[idx] = relpart[idx]
        + p0ws[(size_t)(b * Sn + a0) * TRn + t]
        + p1ws[(size_t)(b * Sn + a1) * TRn + t]
        + rel_b[t];
}

extern "C" void kernel_launch(void* const* d_in, const int* in_sizes, int n_in,
                              void* d_out, int out_size, void* d_ws, size_t ws_size,
                              hipStream_t stream) {
    const float* hid       = (const float*)d_in[0];   // (B,L,H)
    const int*   ent_mask  = (const int*)d_in[1];     // (B,S,L)
    const int*   relations = (const int*)d_in[2];     // (B,R,2)
    const int*   rel_mask  = (const int*)d_in[3];     // (B,R,L)
    const int*   samp_mask = (const int*)d_in[4];     // (B,R)
    const float* size_emb  = (const float*)d_in[5];   // (100,E)
    const float* span_w    = (const float*)d_in[6];   // (2H+E, TE)
    const float* span_b    = (const float*)d_in[7];   // (TE,)
    const float* rel_w     = (const float*)d_in[8];   // (3H+2E, TR)
    const float* rel_b     = (const float*)d_in[9];   // (TR,)

    float* out = (float*)d_out;
    float* out_ent = out;                       // (B,S,TE)
    float* out_rel = out + Bn * Sn * TEn;       // (B,R,TR)

    char* ws = (char*)d_ws;
    float* bmax    = (float*)ws;                              // B*NBLK*H
    float* relpart = bmax + (size_t)Bn * NBLK * Hn;           // B*R*TR
    float* p0ws    = relpart + (size_t)Bn * Rn * TRn;         // B*S*TR
    float* p1ws    = p0ws + (size_t)Bn * Sn * TRn;            // B*S*TR

    blockmax_kernel<<<Bn * NBLK, 192, 0, stream>>>(hid, bmax);

    span_kernel<<<Bn * (Sn + Rn), NTHR, 0, stream>>>(
        hid, ent_mask, rel_mask, samp_mask, size_emb, span_w, span_b,
        rel_w, bmax, relpart, p0ws, p1ws, out_ent);

    combine_kernel<<<(Bn * Rn * TRn + 255) / 256, 256, 0, stream>>>(
        relations, rel_b, relpart, p0ws, p1ws, out_rel);
}

// Round 12
// 22.613 us; speedup vs baseline: 1.3017x; 1.0531x over previous
//
#include <hip/hip_runtime.h>

#define Bn 4
#define Ln 512
#define Hn 768
#define Sn 100
#define Rn 100
#define En 128
#define TEn 8
#define TRn 6
#define NEGF (-1e20f)
#define W 8
#define NBLK (Ln / W)      // 64
#define H4 (Hn / 4)        // 192
#define E4 (En / 4)        // 32
#define NTHR 640           // 10 waves

__device__ __forceinline__ float4 fmax4(float4 a, float4 b) {
    return make_float4(fmaxf(a.x, b.x), fmaxf(a.y, b.y),
                       fmaxf(a.z, b.z), fmaxf(a.w, b.w));
}

// ---------------------------------------------------------------------------
// L1: bmax[b][j][:] = max over rows 8j..8j+7 of hid[b]. 256 blocks x 192 thr.
// ---------------------------------------------------------------------------
__global__ void __launch_bounds__(192)
blockmax_kernel(const float* __restrict__ hid, float* __restrict__ bmax) {
    int bj = blockIdx.x;                   // b*NBLK + j
    int b = bj / NBLK, j = bj % NBLK;
    int tid = threadIdx.x;
    const float4* src = (const float4*)(hid + ((size_t)b * Ln + j * W) * Hn);
    float4 m0 = src[tid];
    float4 m1 = src[(size_t)H4 + tid];
    #pragma unroll
    for (int r = 2; r < W; r += 2) {
        m0 = fmax4(m0, src[(size_t)r * H4 + tid]);
        m1 = fmax4(m1, src[(size_t)(r + 1) * H4 + tid]);
    }
    ((float4*)(bmax + (size_t)bj * Hn))[tid] = fmax4(m0, m1);
}

// wave-level contiguous-span scan -> {start, end} (valid in all lanes)
__device__ __forceinline__ void scan_span(const int* __restrict__ mask,
                                          int lane, int* start, int* end) {
    const int4* m4 = (const int4*)(mask + lane * 8);
    int4 a = m4[0], c = m4[1];
    int mm[8] = {a.x, a.y, a.z, a.w, c.x, c.y, c.z, c.w};
    int first = 0x7fffffff, last = -1;
    #pragma unroll
    for (int r = 0; r < 8; ++r) {
        if (mm[r] != 0) {
            int row = lane * 8 + r;
            first = min(first, row);
            last = max(last, row);
        }
    }
    #pragma unroll
    for (int off = 1; off < 64; off <<= 1) {
        first = min(first, __shfl_xor(first, off, 64));
        last = max(last, __shfl_xor(last, off, 64));
    }
    *start = first;
    *end = last + 1;
}

// hierarchical masked max over rows [start,end): bmax blocks + edge rows
__device__ __forceinline__ float4 span_max(const float4* __restrict__ hb4,
                                           const float4* __restrict__ bm4,
                                           int start, int end) {
    float4 m0 = make_float4(NEGF, NEGF, NEGF, NEGF);
    float4 m1 = m0;
    int jstart = (start + 7) >> 3, jend = end >> 3;
    if (jstart >= jend) {                  // short span: raw rows only
        int r = start;
        for (; r + 2 <= end; r += 2) {
            m0 = fmax4(m0, hb4[(size_t)r * H4]);
            m1 = fmax4(m1, hb4[(size_t)(r + 1) * H4]);
        }
        if (r < end) m0 = fmax4(m0, hb4[(size_t)r * H4]);
        return fmax4(m0, m1);
    }
    int j = jstart;
    for (; j + 4 <= jend; j += 4) {
        m0 = fmax4(m0, fmax4(bm4[(size_t)j * H4], bm4[(size_t)(j + 1) * H4]));
        m1 = fmax4(m1, fmax4(bm4[(size_t)(j + 2) * H4], bm4[(size_t)(j + 3) * H4]));
    }
    for (; j < jend; ++j) m0 = fmax4(m0, bm4[(size_t)j * H4]);
    int he = jstart * W;
    int r = start;
    for (; r + 2 <= he; r += 2) {
        m0 = fmax4(m0, hb4[(size_t)r * H4]);
        m1 = fmax4(m1, hb4[(size_t)(r + 1) * H4]);
    }
    if (r < he) m0 = fmax4(m0, hb4[(size_t)r * H4]);
    r = jend * W;
    for (; r + 2 <= end; r += 2) {
        m0 = fmax4(m0, hb4[(size_t)r * H4]);
        m1 = fmax4(m1, hb4[(size_t)(r + 1) * H4]);
    }
    if (r < end) m0 = fmax4(m0, hb4[(size_t)r * H4]);
    return fmax4(m0, m1);
}

// ---------------------------------------------------------------------------
// L2: 800 blocks x 640 threads, segment-parallel, weights reg-prefetched,
// XCD-chunked block swizzle (each XCD = 100 consecutive blocks = 1 batch-half).
//  entity blk: [0,192) entity | [192,384) ctx | [384,416) size
//  rel blk:    [0,192) relctx | [192,384) e0 | [384,576) e1 | [576,640) s0,s1
// ---------------------------------------------------------------------------
__global__ void __launch_bounds__(NTHR)
logits_kernel(const float* __restrict__ hid,
              const int* __restrict__ ent_mask,
              const int* __restrict__ rel_mask,
              const int* __restrict__ samp_mask,
              const int* __restrict__ relations,
              const float* __restrict__ size_emb,
              const float* __restrict__ span_w,
              const float* __restrict__ span_b,
              const float* __restrict__ rel_w,
              const float* __restrict__ rel_b,
              const float* __restrict__ bmax,
              float* __restrict__ out_ent,
              float* __restrict__ out_rel) {
    // bijective XCD-chunked swizzle: 800 blocks, XCD x handles [x*100,(x+1)*100)
    int blk = (blockIdx.x & 7) * 100 + (blockIdx.x >> 3);
    int tid = threadIdx.x;
    int lane = tid & 63, wv = tid >> 6;

    __shared__ int se[3][2];
    __shared__ float red[10][TEn];

    float acc[TEn];
    #pragma unroll
    for (int t = 0; t < TEn; ++t) acc[t] = 0.0f;

    if (blk < Bn * Sn) {
        // ================= entity logit block =================
        int b = blk / Sn;
        // weight prefetch: span_w rows 4*tid..4*tid+3 (segments contiguous)
        float w32[4 * TEn];
        if (tid < 384 + E4) {
            const float4* wp = (const float4*)(span_w + (size_t)tid * 4 * TEn);
            float4* wreg = (float4*)w32;
            #pragma unroll
            for (int i = 0; i < TEn; ++i) wreg[i] = wp[i];
        }
        if (wv == 0) {
            int s0, e0;
            scan_span(ent_mask + (size_t)blk * Ln, lane, &s0, &e0);
            if (lane == 0) { se[0][0] = s0; se[0][1] = e0; }
        }
        __syncthreads();
        int start = se[0][0], end = se[0][1];
        int cnt = end - start;

        const float4* hb4 = (const float4*)(hid + (size_t)b * Ln * Hn);
        float4 v = make_float4(0.f, 0.f, 0.f, 0.f);
        bool active = true;
        if (tid < 192) {
            const float4* bm4 = (const float4*)(bmax + (size_t)b * NBLK * Hn) + tid;
            v = span_max(hb4 + tid, bm4, start, end);
        } else if (tid < 384) {
            v = hb4[tid - 192];                               // ctx = row 0
        } else if (tid < 384 + E4) {
            v = ((const float4*)(size_emb + (size_t)cnt * En))[tid - 384];
        } else {
            active = false;
        }
        if (active) {
            const float* vp = &v.x;
            #pragma unroll
            for (int j = 0; j < 4; ++j)
                #pragma unroll
                for (int t = 0; t < TEn; ++t)
                    acc[t] += vp[j] * w32[j * TEn + t];
        }

        #pragma unroll
        for (int t = 0; t < TEn; ++t)
            #pragma unroll
            for (int off = 32; off > 0; off >>= 1)
                acc[t] += __shfl_down(acc[t], off, 64);
        if (lane == 0) {
            #pragma unroll
            for (int t = 0; t < TEn; ++t) red[wv][t] = acc[t];
        }
        __syncthreads();
        if (tid < TEn) {
            float s = span_b[tid];
            #pragma unroll
            for (int w = 0; w < 10; ++w) s += red[w][tid];
            out_ent[(size_t)blk * TEn + tid] = s;
        }
    } else {
        // ================= relation logit block =================
        int rblk = blk - Bn * Sn;              // b*R + r
        int b = rblk / Rn;
        int a0 = relations[rblk * 2 + 0];
        int a1 = relations[rblk * 2 + 1];
        bool samp = (samp_mask[rblk] == 1);

        // weight prefetch: rel_w rows 4*tid..4*tid+3 (all 5 segments contiguous)
        float w24[4 * TRn];
        {
            const float4* wp = (const float4*)(rel_w + (size_t)tid * 4 * TRn);
            float4* wreg = (float4*)w24;
            #pragma unroll
            for (int i = 0; i < TRn; ++i) wreg[i] = wp[i];
        }

        if (wv == 0) {
            if (!samp) {
                int s0, e0;
                scan_span(rel_mask + (size_t)rblk * Ln, lane, &s0, &e0);
                if (lane == 0) { se[0][0] = s0; se[0][1] = e0; }
            }
        } else if (wv == 1) {
            int s1, e1;
            scan_span(ent_mask + ((size_t)b * Sn + a0) * Ln, lane, &s1, &e1);
            if (lane == 0) { se[1][0] = s1; se[1][1] = e1; }
        } else if (wv == 2) {
            int s2, e2;
            scan_span(ent_mask + ((size_t)b * Sn + a1) * Ln, lane, &s2, &e2);
            if (lane == 0) { se[2][0] = s2; se[2][1] = e2; }
        }
        __syncthreads();
        int cnt0 = se[1][1] - se[1][0];
        int cnt1 = se[2][1] - se[2][0];

        const float4* hb4 = (const float4*)(hid + (size_t)b * Ln * Hn);
        const float4* bm4 = (const float4*)(bmax + (size_t)b * NBLK * Hn);
        float4 v = make_float4(0.f, 0.f, 0.f, 0.f);
        bool active = true;
        if (tid < 192) {
            if (samp) active = false;
            else v = span_max(hb4 + tid, bm4 + tid, se[0][0], se[0][1]);
        } else if (tid < 384) {
            int u = tid - 192;
            v = span_max(hb4 + u, bm4 + u, se[1][0], se[1][1]);
        } else if (tid < 576) {
            int u = tid - 384;
            v = span_max(hb4 + u, bm4 + u, se[2][0], se[2][1]);
        } else if (tid < 576 + E4) {
            v = ((const float4*)(size_emb + (size_t)cnt0 * En))[tid - 576];
        } else {
            v = ((const float4*)(size_emb + (size_t)cnt1 * En))[tid - 576 - E4];
        }
        if (active) {
            const float* vp = &v.x;
            #pragma unroll
            for (int j = 0; j < 4; ++j)
                #pragma unroll
                for (int t = 0; t < TRn; ++t)
                    acc[t] += vp[j] * w24[j * TRn + t];
        }

        #pragma unroll
        for (int t = 0; t < TRn; ++t)
            #pragma unroll
            for (int off = 32; off > 0; off >>= 1)
                acc[t] += __shfl_down(acc[t], off, 64);
        if (lane == 0) {
            #pragma unroll
            for (int t = 0; t < TRn; ++t) red[wv][t] = acc[t];
        }
        __syncthreads();
        if (tid < TRn) {
            float s = rel_b[tid];
            #pragma unroll
            for (int w = 0; w < 10; ++w) s += red[w][tid];
            out_rel[(size_t)rblk * TRn + tid] = s;
        }
    }
}

extern "C" void kernel_launch(void* const* d_in, const int* in_sizes, int n_in,
                              void* d_out, int out_size, void* d_ws, size_t ws_size,
                              hipStream_t stream) {
    const float* hid       = (const float*)d_in[0];   // (B,L,H)
    const int*   ent_mask  = (const int*)d_in[1];     // (B,S,L)
    const int*   relations = (const int*)d_in[2];     // (B,R,2)
    const int*   rel_mask  = (const int*)d_in[3];     // (B,R,L)
    const int*   samp_mask = (const int*)d_in[4];     // (B,R)
    const float* size_emb  = (const float*)d_in[5];   // (100,E)
    const float* span_w    = (const float*)d_in[6];   // (2H+E, TE)
    const float* span_b    = (const float*)d_in[7];   // (TE,)
    const float* rel_w     = (const float*)d_in[8];   // (3H+2E, TR)
    const float* rel_b     = (const float*)d_in[9];   // (TR,)

    float* out = (float*)d_out;
    float* out_ent = out;                       // (B,S,TE)
    float* out_rel = out + Bn * Sn * TEn;       // (B,R,TR)

    float* bmax = (float*)d_ws;                 // B*NBLK*H floats (~786 KB)

    blockmax_kernel<<<Bn * NBLK, 192, 0, stream>>>(hid, bmax);

    logits_kernel<<<Bn * (Sn + Rn), NTHR, 0, stream>>>(
        hid, ent_mask, rel_mask, samp_mask, relations, size_emb,
        span_w, span_b, rel_w, rel_b, bmax, out_ent, out_rel);
}